// Round 15
// baseline (211.159 us; speedup 1.0000x reference)
//
#include <hip/hip_runtime.h>
#include <hip/hip_bf16.h>
#include <math.h>

// Problem constants
#define D_MODEL 1024
#define D_STATE 16
#define D_CONV 4
#define D_INNER 2048
#define BATCH 2
#define SEQ 4096
#define NROW (BATCH * SEQ)          // 8192 rows (b*L + t)
#define LN_EPS 1e-5f

typedef __attribute__((ext_vector_type(8))) short  bf16x8_t;   // 8 bf16 (4 VGPRs)
typedef __attribute__((ext_vector_type(4))) float  f32x4_t;    // MFMA accumulator
typedef __attribute__((ext_vector_type(8))) unsigned short u16x8_t;

// round-to-nearest-even f32 -> bf16 (no NaN handling; data is finite)
__device__ inline unsigned short f2bf(float f) {
    unsigned u = __float_as_uint(f);
    u += 0x7fffu + ((u >> 16) & 1u);
    return (unsigned short)(u >> 16);
}
__device__ inline float bf2f(unsigned short u) {
    return __uint_as_float((unsigned)u << 16);
}

#define GLL16(g, l)                                                            \
    __builtin_amdgcn_global_load_lds(                                          \
        (const __attribute__((address_space(1))) void*)(g),                    \
        (__attribute__((address_space(3))) void*)(l), 16, 0, 0)

#define FENCE asm volatile("" ::: "memory")
#define BAR do { FENCE; __builtin_amdgcn_s_barrier(); FENCE; } while (0)

// ---------------------------------------------------------------------------
// 0+1. Fused weight-conversion + LayerNorm (block-per-row LN).
// ---------------------------------------------------------------------------
#define CVT_BLOCKS 3088
__global__ __launch_bounds__(256) void pre_kernel(const float* __restrict__ x,
                                                  const float* __restrict__ gamma,
                                                  const float* __restrict__ beta,
                                                  const float* __restrict__ W_in,
                                                  const float* __restrict__ W_out,
                                                  const float* __restrict__ Bm,
                                                  unsigned short* __restrict__ xn,
                                                  unsigned short* __restrict__ Win_bf,
                                                  unsigned short* __restrict__ Wout_bf,
                                                  unsigned short* __restrict__ Bm_bf) {
    __shared__ float red[8];
    const int tid = threadIdx.x;
    if (blockIdx.x < CVT_BLOCKS) {
        const long long g = (long long)(blockIdx.x * 256 + tid) * 8;
        const long long n1 = (long long)2 * D_INNER * D_MODEL;      // 4194304
        const long long n2 = n1 + (long long)D_MODEL * D_INNER;     // +2097152
        const float* src; unsigned short* dst; long long off;
        if (g < n1)      { src = W_in;  dst = Win_bf;  off = g; }
        else if (g < n2) { src = W_out; dst = Wout_bf; off = g - n1; }
        else             { src = Bm;    dst = Bm_bf;   off = g - n2; }
        const float4 a = *reinterpret_cast<const float4*>(src + off);
        const float4 b = *reinterpret_cast<const float4*>(src + off + 4);
        u16x8_t p;
        p[0] = f2bf(a.x); p[1] = f2bf(a.y); p[2] = f2bf(a.z); p[3] = f2bf(a.w);
        p[4] = f2bf(b.x); p[5] = f2bf(b.y); p[6] = f2bf(b.z); p[7] = f2bf(b.w);
        *reinterpret_cast<u16x8_t*>(dst + off) = p;
        return;
    }
    const int row = blockIdx.x - CVT_BLOCKS;
    const float4* xr = reinterpret_cast<const float4*>(x + (size_t)row * D_MODEL);
    float4 v = xr[tid];

    const int lane = tid & 63, wave = tid >> 6;
    float s = v.x + v.y + v.z + v.w;
    #pragma unroll
    for (int off = 32; off > 0; off >>= 1) s += __shfl_down(s, off, 64);
    if (lane == 0) red[wave] = s;
    __syncthreads();
    float mu = (red[0] + red[1] + red[2] + red[3]) * (1.0f / D_MODEL);
    __syncthreads();

    float dx = v.x - mu, dy = v.y - mu, dz = v.z - mu, dw = v.w - mu;
    float ss = dx * dx + dy * dy + dz * dz + dw * dw;
    #pragma unroll
    for (int off = 32; off > 0; off >>= 1) ss += __shfl_down(ss, off, 64);
    if (lane == 0) red[wave] = ss;
    __syncthreads();
    float var = (red[0] + red[1] + red[2] + red[3]) * (1.0f / D_MODEL);
    float rs = rsqrtf(var + LN_EPS);

    const float4 gv = reinterpret_cast<const float4*>(gamma)[tid];
    const float4 bv = reinterpret_cast<const float4*>(beta)[tid];
    ushort4 o;
    o.x = f2bf(dx * rs * gv.x + bv.x);
    o.y = f2bf(dy * rs * gv.y + bv.y);
    o.z = f2bf(dz * rs * gv.z + bv.z);
    o.w = f2bf(dw * rs * gv.w + bv.w);
    reinterpret_cast<ushort4*>(xn + (size_t)row * D_MODEL)[tid] = o;
}

// ---------------------------------------------------------------------------
// 2a. 256x256 bf16 MFMA GEMM (TN), bf16 output. (GEMM1) — r12 known-good.
// ---------------------------------------------------------------------------
__global__ __launch_bounds__(512, 2) void gemm256_bf16(const short* __restrict__ A,
                                                       const short* __restrict__ B,
                                                       unsigned short* __restrict__ Cb,
                                                       int M, int N, int K) {
    __shared__ short lds[2 * 4 * 8192];   // 128 KiB

    const int tid = threadIdx.x;
    const int w = tid >> 6, l = tid & 63;

    const int id = blockIdx.y * gridDim.x + blockIdx.x;
    const int cpx = (gridDim.x * gridDim.y) >> 3;
    const int sid = (id & 7) * cpx + (id >> 3);
    const int row0 = (sid / gridDim.x) * 256;
    const int col0 = (sid % gridDim.x) * 256;

    const int wm = w >> 2;
    const int wn = w & 3;
    const int fr = l & 15;
    const int fc = (l >> 4) * 8;
    const int NT = K >> 6;

    const int qa = wm;
    const int qb = 2 + (wn >> 1);
    const int bb = (wn & 1) * 64;

    auto STAGE = [&](const short* __restrict__ G, int growbase, int k0,
                     int buf, int q) {
        #pragma unroll
        for (int j = 0; j < 2; ++j) {
            const int e = ((j * 8 + w) << 9) + l * 8;
            const int r = e >> 6;
            const int c = (e & 63) ^ ((r & 7) << 3);
            GLL16(G + (size_t)(growbase + r) * K + k0 + c,
                  &lds[buf * 32768 + q * 8192 + ((j * 8 + w) << 9)]);
        }
    };
    auto LDF = [&](int buf, int q, int r, int ks) -> bf16x8_t {
        const int c = (ks * 32 + fc) ^ ((r & 7) << 3);
        return *reinterpret_cast<const bf16x8_t*>(
            &lds[buf * 32768 + q * 8192 + r * 64 + c]);
    };

    f32x4_t acc[8][4] = {};
    bf16x8_t af[4][2], af2[4][2], bA[2][2], bB[2][2];

#define MFMA_Q(AF, mh, nh, BFR)                                                \
    do {                                                                       \
        _Pragma("unroll")                                                      \
        for (int mi = 0; mi < 4; ++mi)                                         \
            _Pragma("unroll")                                                  \
            for (int ni = 0; ni < 2; ++ni)                                     \
                _Pragma("unroll")                                              \
                for (int ks = 0; ks < 2; ++ks)                                 \
                    acc[(mh) * 4 + mi][(nh) * 2 + ni] =                        \
                        __builtin_amdgcn_mfma_f32_16x16x32_bf16(               \
                            AF[mi][ks], BFR[ni][ks],                           \
                            acc[(mh) * 4 + mi][(nh) * 2 + ni], 0, 0, 0);       \
    } while (0)

    STAGE(A, row0,       0, 0, 0);
    STAGE(A, row0 + 128, 0, 0, 1);
    STAGE(B, col0,       0, 0, 2);
    STAGE(B, col0 + 128, 0, 0, 3);
    if (NT > 1) {
        STAGE(B, col0,       64, 1, 2);
        STAGE(B, col0 + 128, 64, 1, 3);
        STAGE(A, row0,       64, 1, 0);
        asm volatile("s_waitcnt vmcnt(6)" ::: "memory");
    } else {
        asm volatile("s_waitcnt vmcnt(0)" ::: "memory");
    }
    BAR;

    for (int kt = 0; kt < NT; ++kt) {
        const int buf = kt & 1, nbuf = buf ^ 1;
        #pragma unroll
        for (int mi = 0; mi < 4; ++mi)
            #pragma unroll
            for (int ks = 0; ks < 2; ++ks)
                af[mi][ks] = LDF(buf, qa, mi * 16 + fr, ks);
        #pragma unroll
        for (int ni = 0; ni < 2; ++ni)
            #pragma unroll
            for (int ks = 0; ks < 2; ++ks)
                bA[ni][ks] = LDF(buf, qb, bb + ni * 16 + fr, ks);
        #pragma unroll
        for (int ni = 0; ni < 2; ++ni)
            #pragma unroll
            for (int ks = 0; ks < 2; ++ks)
                bB[ni][ks] = LDF(buf, qb, bb + 32 + ni * 16 + fr, ks);
        #pragma unroll
        for (int mi = 0; mi < 4; ++mi)
            #pragma unroll
            for (int ks = 0; ks < 2; ++ks)
                af2[mi][ks] = LDF(buf, qa, 64 + mi * 16 + fr, ks);
        if (kt + 1 < NT) STAGE(A, row0 + 128, (kt + 1) << 6, nbuf, 1);
        asm volatile("s_waitcnt lgkmcnt(0)" ::: "memory");
        BAR;
        if (kt + 2 < NT) {
            STAGE(B, col0,       (kt + 2) << 6, buf, 2);
            STAGE(B, col0 + 128, (kt + 2) << 6, buf, 3);
            STAGE(A, row0,       (kt + 2) << 6, buf, 0);
            asm volatile("s_waitcnt vmcnt(6)" ::: "memory");
        } else {
            asm volatile("s_waitcnt vmcnt(0)" ::: "memory");
        }
        BAR;
        __builtin_amdgcn_s_setprio(1);
        MFMA_Q(af,  0, 0, bA);
        MFMA_Q(af,  0, 1, bB);
        MFMA_Q(af2, 1, 1, bB);
        MFMA_Q(af2, 1, 0, bA);
        __builtin_amdgcn_s_setprio(0);
    }
#undef MFMA_Q

    const int cr = (l >> 4) * 4;
    const int cc = l & 15;
    #pragma unroll
    for (int m = 0; m < 8; ++m) {
        #pragma unroll
        for (int n = 0; n < 4; ++n) {
            size_t base = (size_t)(row0 + wm * 128 + m * 16 + cr) * N +
                          (col0 + wn * 64 + n * 16 + cc);
            #pragma unroll
            for (int j = 0; j < 4; ++j)
                Cb[base + (size_t)j * N] = f2bf(acc[m][n][j]);
        }
    }
}

// ---------------------------------------------------------------------------
// 2b. 256x128-tile bf16 MFMA GEMM (TN), f32 out + residual. (GEMM2)
//     3-buf 1-barrier + 4M×2N wave decomposition. — r14 known-good.
// ---------------------------------------------------------------------------
__global__ __launch_bounds__(512) void gemm_out(const short* __restrict__ A,
                                                const short* __restrict__ B,
                                                const float* __restrict__ add,
                                                float* __restrict__ C,
                                                int M, int N, int K) {
    __shared__ short lds[3 * 3 * 8192];   // 144 KiB

    const int tid = threadIdx.x;
    const int w = tid >> 6, l = tid & 63;

    const int id = blockIdx.y * gridDim.x + blockIdx.x;
    const int cpx = (gridDim.x * gridDim.y) >> 3;
    const int sid = (id & 7) * cpx + (id >> 3);
    const int row0 = (sid / gridDim.x) * 256;
    const int col0 = (sid % gridDim.x) * 128;

    const int wm = w >> 1;               // 0..3  (64-row strip)
    const int wn = w & 1;                // 0..1  (64-col strip)
    const int qa = wm >> 1;              // A quarter (0 or 1)
    const int lr0 = (wm & 1) * 64;       // local row base within quarter
    const int fr = l & 15;
    const int fc = (l >> 4) * 8;
    const int NT = K >> 6;

    auto STAGE = [&](const short* __restrict__ G, int growbase, int k0,
                     int buf, int q) {
        #pragma unroll
        for (int j = 0; j < 2; ++j) {
            const int e = ((j * 8 + w) << 9) + l * 8;
            const int r = e >> 6;
            const int c = (e & 63) ^ ((r & 7) << 3);
            GLL16(G + (size_t)(growbase + r) * K + k0 + c,
                  &lds[buf * 24576 + q * 8192 + ((j * 8 + w) << 9)]);
        }
    };
    auto LDF = [&](int buf, int q, int r, int ks) -> bf16x8_t {
        const int c = (ks * 32 + fc) ^ ((r & 7) << 3);
        return *reinterpret_cast<const bf16x8_t*>(
            &lds[buf * 24576 + q * 8192 + r * 64 + c]);
    };

    f32x4_t acc[4][4] = {};
    bf16x8_t af[4][2], bf[4][2];

    STAGE(A, row0,       0, 0, 0);
    STAGE(A, row0 + 128, 0, 0, 1);
    STAGE(B, col0,       0, 0, 2);
    if (NT > 1) {
        STAGE(A, row0,       64, 1, 0);
        STAGE(A, row0 + 128, 64, 1, 1);
        STAGE(B, col0,       64, 1, 2);
        asm volatile("s_waitcnt vmcnt(6)" ::: "memory");
    } else {
        asm volatile("s_waitcnt vmcnt(0)" ::: "memory");
    }

    int buf = 0;
    for (int kt = 0; kt < NT; ++kt) {
        BAR;
        #pragma unroll
        for (int mi = 0; mi < 4; ++mi)
            #pragma unroll
            for (int ks = 0; ks < 2; ++ks)
                af[mi][ks] = LDF(buf, qa, lr0 + mi * 16 + fr, ks);
        #pragma unroll
        for (int ni = 0; ni < 4; ++ni)
            #pragma unroll
            for (int ks = 0; ks < 2; ++ks)
                bf[ni][ks] = LDF(buf, 2, wn * 64 + ni * 16 + fr, ks);
        __builtin_amdgcn_s_setprio(1);
        #pragma unroll
        for (int mi = 0; mi < 4; ++mi)
            #pragma unroll
            for (int ni = 0; ni < 4; ++ni)
                #pragma unroll
                for (int ks = 0; ks < 2; ++ks)
                    acc[mi][ni] = __builtin_amdgcn_mfma_f32_16x16x32_bf16(
                        af[mi][ks], bf[ni][ks], acc[mi][ni], 0, 0, 0);
        __builtin_amdgcn_s_setprio(0);
        if (kt + 2 < NT) {
            const int sb = (buf + 2) % 3;
            STAGE(A, row0,       (kt + 2) << 6, sb, 0);
            STAGE(A, row0 + 128, (kt + 2) << 6, sb, 1);
            STAGE(B, col0,       (kt + 2) << 6, sb, 2);
            asm volatile("s_waitcnt vmcnt(6)" ::: "memory");
        } else {
            asm volatile("s_waitcnt vmcnt(0)" ::: "memory");
        }
        buf = (buf + 1) % 3;
    }

    const int cr = (l >> 4) * 4;
    const int cc = l & 15;
    #pragma unroll
    for (int mi = 0; mi < 4; ++mi) {
        #pragma unroll
        for (int ni = 0; ni < 4; ++ni) {
            size_t base = (size_t)(row0 + wm * 64 + mi * 16 + cr) * N +
                          (col0 + wn * 64 + ni * 16 + cc);
            #pragma unroll
            for (int j = 0; j < 4; ++j)
                C[base + (size_t)j * N] = acc[mi][ni][j] + add[base + (size_t)j * N];
        }
    }
}

// ---------------------------------------------------------------------------
// 3. V = x_part @ Bm^T via MFMA (K=2048). NEW: 2 waves/block split-K
//    (each wave half of K, 4 ILP chains each; LDS merge) -> 1024 waves.
// ---------------------------------------------------------------------------
__global__ __launch_bounds__(128) void v_mfma(const unsigned short* __restrict__ xz,
                                              const unsigned short* __restrict__ Bmb,
                                              float* __restrict__ V) {
    __shared__ float part[2][16][16];
    const int tid = threadIdx.x;
    const int wv = tid >> 6;             // 0..1 : K half
    const int l = tid & 63;
    const int r0 = blockIdx.x * 16;
    const int fr = l & 15;
    const int fk = (l >> 4) * 8;
    const int kbase = wv * (D_INNER / 2);

    const unsigned short* aP = xz + (size_t)(r0 + fr) * (2 * D_INNER) + kbase + fk;
    const unsigned short* bP = Bmb + fr * D_INNER + kbase + fk;

    f32x4_t a0 = {}, a1 = {}, a2 = {}, a3 = {};
    #pragma unroll 2
    for (int k0 = 0; k0 < D_INNER / 2; k0 += 128) {
        a0 = __builtin_amdgcn_mfma_f32_16x16x32_bf16(
            *reinterpret_cast<const bf16x8_t*>(aP + k0),
            *reinterpret_cast<const bf16x8_t*>(bP + k0), a0, 0, 0, 0);
        a1 = __builtin_amdgcn_mfma_f32_16x16x32_bf16(
            *reinterpret_cast<const bf16x8_t*>(aP + k0 + 32),
            *reinterpret_cast<const bf16x8_t*>(bP + k0 + 32), a1, 0, 0, 0);
        a2 = __builtin_amdgcn_mfma_f32_16x16x32_bf16(
            *reinterpret_cast<const bf16x8_t*>(aP + k0 + 64),
            *reinterpret_cast<const bf16x8_t*>(bP + k0 + 64), a2, 0, 0, 0);
        a3 = __builtin_amdgcn_mfma_f32_16x16x32_bf16(
            *reinterpret_cast<const bf16x8_t*>(aP + k0 + 96),
            *reinterpret_cast<const bf16x8_t*>(bP + k0 + 96), a3, 0, 0, 0);
    }

    const int cr = (l >> 4) * 4;
    const int cc = l & 15;
    #pragma unroll
    for (int j = 0; j < 4; ++j)
        part[wv][cr + j][cc] = a0[j] + a1[j] + a2[j] + a3[j];
    __syncthreads();
    if (tid < 64) {
        #pragma unroll
        for (int j = 0; j < 4; ++j)
            V[(size_t)(r0 + cr + j) * D_STATE + cc] =
                part[0][cr + j][cc] + part[1][cr + j][cc];
    }
}

// ---------------------------------------------------------------------------
// 4. Fused scan: blocks 0..31 = parallel cumsum (A == I); block 32 =
//    sequential general-A fallback. Both self-check A; exactly one side runs.
// ---------------------------------------------------------------------------
#define SCAN_CHUNK 256
__global__ __launch_bounds__(256) void scan_fused(const float* __restrict__ V,
                                                  const float* __restrict__ A,
                                                  float* __restrict__ S) {
    const int tid = threadIdx.x;
    __shared__ int nid;
    if (blockIdx.x < 32) {
        // ---- parallel path (A == I)
        if (tid == 0) nid = 0;
        __syncthreads();
        {
            const float ex = ((tid >> 4) == (tid & 15)) ? 1.0f : 0.0f;
            if (A[tid] != ex) atomicOr(&nid, 1);
        }
        __syncthreads();
        if (nid) return;

        const int p = blockIdx.x;
        const int b = p >> 4, s = p & 15;
        const float* vb = V + (size_t)b * SEQ * D_STATE + s;
        float* sb = S + (size_t)b * SEQ * D_STATE + s;

        const int t0 = tid * 16;
        float v[16];
        float run = 0.0f;
        #pragma unroll
        for (int j = 0; j < 16; ++j) {
            run += vb[(size_t)(t0 + j) * D_STATE];
            v[j] = run;
        }

        const float tot = run;
        float sc = tot;
        #pragma unroll
        for (int off = 1; off < 64; off <<= 1) {
            float n = __shfl_up(sc, off, 64);
            if ((tid & 63) >= off) sc += n;
        }
        __shared__ float wtot[4];
        if ((tid & 63) == 63) wtot[tid >> 6] = sc;
        __syncthreads();
        float woff = 0.0f;
        #pragma unroll
        for (int w2 = 0; w2 < 4; ++w2)
            if (w2 < (tid >> 6)) woff += wtot[w2];
        const float excl = sc - tot + woff;

        #pragma unroll
        for (int j = 0; j < 16; ++j)
            sb[(size_t)(t0 + j) * D_STATE] = v[j] + excl;
        return;
    }

    // ---- sequential general-A path (block 32; 256 threads assist I/O)
    if (tid == 0) nid = 0;
    __syncthreads();
    {
        const float ex = ((tid >> 4) == (tid & 15)) ? 1.0f : 0.0f;
        if (A[tid] != ex) atomicOr(&nid, 1);
    }
    __syncthreads();
    if (nid == 0) return;   // identity -> parallel blocks handled it

    __shared__ float Al[D_STATE * D_STATE];
    __shared__ float Vl[2 * SCAN_CHUNK * D_STATE];
    __shared__ float Sl[2 * SCAN_CHUNK * D_STATE];

    Al[tid] = A[tid];
    __syncthreads();

    float st = 0.0f;
    const int bb = (tid >> 4) & 1;
    const int ss = tid & 15;

    for (int t0 = 0; t0 < SEQ; t0 += SCAN_CHUNK) {
        for (int idx = tid; idx < 2 * SCAN_CHUNK * D_STATE; idx += 256) {
            int b = idx >> 12;
            int rem = idx & 4095;
            Vl[idx] = V[((size_t)(b * SEQ + t0) * D_STATE) + rem];
        }
        __syncthreads();

        if (tid < 32) {
            float* vb = Vl + bb * SCAN_CHUNK * D_STATE + ss;
            float* sb = Sl + bb * SCAN_CHUNK * D_STATE + ss;
            for (int t = 0; t < SCAN_CHUNK; ++t) {
                float ns = vb[t * D_STATE];
                #pragma unroll
                for (int s2 = 0; s2 < D_STATE; ++s2) {
                    float other = __shfl(st, (tid & 16) | s2, 64);
                    ns = fmaf(Al[ss * D_STATE + s2], other, ns);
                }
                st = ns;
                sb[t * D_STATE] = st;
            }
        }
        __syncthreads();

        for (int idx = tid; idx < 2 * SCAN_CHUNK * D_STATE; idx += 256) {
            int b = idx >> 12;
            int rem = idx & 4095;
            S[((size_t)(b * SEQ + t0) * D_STATE) + rem] = Sl[idx];
        }
        __syncthreads();
    }
}

// ---------------------------------------------------------------------------
// 5. y = (silu(conv(x_part)) + S @ Cm) * sigmoid(z)  -> bf16 output.
//    NEW: 4 columns/thread (ushort4 = 8B loads, coalescing sweet spot).
// ---------------------------------------------------------------------------
__global__ __launch_bounds__(256) void y_kernel(const unsigned short* __restrict__ xz,
                                                const float* __restrict__ S,
                                                const float* __restrict__ Cm,
                                                const float* __restrict__ convw,
                                                const float* __restrict__ convb,
                                                unsigned short* __restrict__ y) {
    const int tid = threadIdx.x;
    const int i0 = blockIdx.x * 1024 + tid * 4;
    const int r0 = blockIdx.y * 64;
    const int tb0 = r0 & (SEQ - 1);

    float4 w[4];
    #pragma unroll
    for (int c = 0; c < 4; ++c)
        w[c] = *reinterpret_cast<const float4*>(&convw[(i0 + c) * D_CONV]);
    const float4 cb = *reinterpret_cast<const float4*>(&convb[i0]);
    const float cbv[4] = {cb.x, cb.y, cb.z, cb.w};
    float cm[4][D_STATE];
    #pragma unroll
    for (int s = 0; s < D_STATE; ++s) {
        float4 c = *reinterpret_cast<const float4*>(&Cm[s * D_INNER + i0]);
        cm[0][s] = c.x; cm[1][s] = c.y; cm[2][s] = c.z; cm[3][s] = c.w;
    }

    float xm1[4] = {}, xm2[4] = {}, xm3[4] = {};
    if (tb0 >= 1) { ushort4 u = *reinterpret_cast<const ushort4*>(&xz[(size_t)(r0 - 1) * (2 * D_INNER) + i0]);
                    xm1[0] = bf2f(u.x); xm1[1] = bf2f(u.y); xm1[2] = bf2f(u.z); xm1[3] = bf2f(u.w); }
    if (tb0 >= 2) { ushort4 u = *reinterpret_cast<const ushort4*>(&xz[(size_t)(r0 - 2) * (2 * D_INNER) + i0]);
                    xm2[0] = bf2f(u.x); xm2[1] = bf2f(u.y); xm2[2] = bf2f(u.z); xm2[3] = bf2f(u.w); }
    if (tb0 >= 3) { ushort4 u = *reinterpret_cast<const ushort4*>(&xz[(size_t)(r0 - 3) * (2 * D_INNER) + i0]);
                    xm3[0] = bf2f(u.x); xm3[1] = bf2f(u.y); xm3[2] = bf2f(u.z); xm3[3] = bf2f(u.w); }

    for (int r = r0; r < r0 + 64; ++r) {
        const ushort4 xu = *reinterpret_cast<const ushort4*>(&xz[(size_t)r * (2 * D_INNER) + i0]);
        const ushort4 zu = *reinterpret_cast<const ushort4*>(&xz[(size_t)r * (2 * D_INNER) + D_INNER + i0]);
        const float x0[4] = {bf2f(xu.x), bf2f(xu.y), bf2f(xu.z), bf2f(xu.w)};
        const float zv[4] = {bf2f(zu.x), bf2f(zu.y), bf2f(zu.z), bf2f(zu.w)};

        const float4* Sp = reinterpret_cast<const float4*>(S + (size_t)r * D_STATE);
        const float4 s0 = Sp[0], s1 = Sp[1], s2 = Sp[2], s3 = Sp[3];
        const float sv[D_STATE] = {s0.x, s0.y, s0.z, s0.w, s1.x, s1.y, s1.z, s1.w,
                                   s2.x, s2.y, s2.z, s2.w, s3.x, s3.y, s3.z, s3.w};

        ushort4 o;
        unsigned short* op = reinterpret_cast<unsigned short*>(&o);
        #pragma unroll
        for (int c = 0; c < 4; ++c) {
            float a = cbv[c];
            a = fmaf(w[c].x, xm3[c], a); a = fmaf(w[c].y, xm2[c], a);
            a = fmaf(w[c].z, xm1[c], a); a = fmaf(w[c].w, x0[c], a);
            const float xc = a / (1.0f + expf(-a));
            float sc = 0.f;
            #pragma unroll
            for (int s = 0; s < D_STATE; ++s) sc = fmaf(sv[s], cm[c][s], sc);
            const float g = 1.0f / (1.0f + expf(-zv[c]));
            op[c] = f2bf((xc + sc) * g);
            xm3[c] = xm2[c]; xm2[c] = xm1[c]; xm1[c] = x0[c];
        }
        *reinterpret_cast<ushort4*>(&y[(size_t)r * D_INNER + i0]) = o;
    }
}

// ---------------------------------------------------------------------------
// launch
// ---------------------------------------------------------------------------
extern "C" void kernel_launch(void* const* d_in, const int* in_sizes, int n_in,
                              void* d_out, int out_size, void* d_ws, size_t ws_size,
                              hipStream_t stream) {
    const float* x      = (const float*)d_in[0];
    const float* ln_g   = (const float*)d_in[1];
    const float* ln_b   = (const float*)d_in[2];
    const float* W_in   = (const float*)d_in[3];
    const float* conv_w = (const float*)d_in[4];
    const float* conv_b = (const float*)d_in[5];
    const float* W_out  = (const float*)d_in[6];
    const float* A      = (const float*)d_in[7];
    const float* Bm     = (const float*)d_in[8];
    const float* Cm     = (const float*)d_in[9];
    float* out = (float*)d_out;

    // workspace layout
    float* ws = (float*)d_ws;
    float* V  = ws;                                        // 8192*16 f32
    float* S  = V + (size_t)NROW * D_STATE;                // 8192*16 f32
    unsigned short* xz_bf  = (unsigned short*)(S + (size_t)NROW * D_STATE);
    unsigned short* xn_bf  = xz_bf  + (size_t)NROW * 2 * D_INNER;
    unsigned short* Win_bf = xn_bf  + (size_t)NROW * D_MODEL;
    unsigned short* Wout_bf= Win_bf + (size_t)(2 * D_INNER) * D_MODEL;
    unsigned short* Bm_bf  = Wout_bf + (size_t)D_MODEL * D_INNER;
    unsigned short* y_bf   = Bm_bf  + (size_t)D_STATE * D_INNER;

    // 0+1. weight conversion + LayerNorm (fused launch, block-per-row LN)
    pre_kernel<<<CVT_BLOCKS + NROW, 256, 0, stream>>>(
        x, ln_g, ln_b, W_in, W_out, Bm, xn_bf, Win_bf, Wout_bf, Bm_bf);

    // 2. xz = xn @ W_in^T -> bf16   (M=8192, N=4096, K=1024), 2-barrier/kt
    gemm256_bf16<<<dim3((2 * D_INNER) / 256, NROW / 256), 512, 0, stream>>>(
        (const short*)xn_bf, (const short*)Win_bf, xz_bf,
        NROW, 2 * D_INNER, D_MODEL);

    // 3. V = x_part @ Bm^T  (MFMA, split-K x2, 4 ILP chains per wave)
    v_mfma<<<NROW / 16, 128, 0, stream>>>(xz_bf, Bm_bf, V);

    // 4. fused scan (blocks 0-31 parallel, block 32 sequential fallback)
    scan_fused<<<33, 256, 0, stream>>>(V, A, S);

    // 5. y = (silu(conv(x_part)) + S@Cm) * sigmoid(z) -> bf16 (4 cols/thr)
    y_kernel<<<dim3(D_INNER / 1024, NROW / 64), 256, 0, stream>>>(
        xz_bf, S, Cm, conv_w, conv_b, y_bf);

    // 6. out = x + y @ W_out^T  (M=8192, N=1024, K=2048), 3-buf 1-bar, 4Mx2N
    gemm_out<<<dim3(D_MODEL / 128, NROW / 256), 512, 0, stream>>>(
        (const short*)y_bf, (const short*)Wout_bf, x, out,
        NROW, D_MODEL, D_INNER);
}

// Round 16
// 187.576 us; speedup vs baseline: 1.1257x; 1.1257x over previous
//
#include <hip/hip_runtime.h>
#include <hip/hip_bf16.h>
#include <math.h>

// Problem constants
#define D_MODEL 1024
#define D_STATE 16
#define D_CONV 4
#define D_INNER 2048
#define BATCH 2
#define SEQ 4096
#define NROW (BATCH * SEQ)          // 8192 rows (b*L + t)
#define LN_EPS 1e-5f

typedef __attribute__((ext_vector_type(8))) short  bf16x8_t;   // 8 bf16 (4 VGPRs)
typedef __attribute__((ext_vector_type(4))) float  f32x4_t;    // MFMA accumulator
typedef __attribute__((ext_vector_type(8))) unsigned short u16x8_t;

// round-to-nearest-even f32 -> bf16 (no NaN handling; data is finite)
__device__ inline unsigned short f2bf(float f) {
    unsigned u = __float_as_uint(f);
    u += 0x7fffu + ((u >> 16) & 1u);
    return (unsigned short)(u >> 16);
}
__device__ inline float bf2f(unsigned short u) {
    return __uint_as_float((unsigned)u << 16);
}

#define GLL16(g, l)                                                            \
    __builtin_amdgcn_global_load_lds(                                          \
        (const __attribute__((address_space(1))) void*)(g),                    \
        (__attribute__((address_space(3))) void*)(l), 16, 0, 0)

#define FENCE asm volatile("" ::: "memory")
#define BAR do { FENCE; __builtin_amdgcn_s_barrier(); FENCE; } while (0)

// ---------------------------------------------------------------------------
// 0+1. Fused weight-conversion + LayerNorm (block-per-row LN).
// ---------------------------------------------------------------------------
#define CVT_BLOCKS 3088
__global__ __launch_bounds__(256) void pre_kernel(const float* __restrict__ x,
                                                  const float* __restrict__ gamma,
                                                  const float* __restrict__ beta,
                                                  const float* __restrict__ W_in,
                                                  const float* __restrict__ W_out,
                                                  const float* __restrict__ Bm,
                                                  unsigned short* __restrict__ xn,
                                                  unsigned short* __restrict__ Win_bf,
                                                  unsigned short* __restrict__ Wout_bf,
                                                  unsigned short* __restrict__ Bm_bf) {
    __shared__ float red[8];
    const int tid = threadIdx.x;
    if (blockIdx.x < CVT_BLOCKS) {
        const long long g = (long long)(blockIdx.x * 256 + tid) * 8;
        const long long n1 = (long long)2 * D_INNER * D_MODEL;      // 4194304
        const long long n2 = n1 + (long long)D_MODEL * D_INNER;     // +2097152
        const float* src; unsigned short* dst; long long off;
        if (g < n1)      { src = W_in;  dst = Win_bf;  off = g; }
        else if (g < n2) { src = W_out; dst = Wout_bf; off = g - n1; }
        else             { src = Bm;    dst = Bm_bf;   off = g - n2; }
        const float4 a = *reinterpret_cast<const float4*>(src + off);
        const float4 b = *reinterpret_cast<const float4*>(src + off + 4);
        u16x8_t p;
        p[0] = f2bf(a.x); p[1] = f2bf(a.y); p[2] = f2bf(a.z); p[3] = f2bf(a.w);
        p[4] = f2bf(b.x); p[5] = f2bf(b.y); p[6] = f2bf(b.z); p[7] = f2bf(b.w);
        *reinterpret_cast<u16x8_t*>(dst + off) = p;
        return;
    }
    const int row = blockIdx.x - CVT_BLOCKS;
    const float4* xr = reinterpret_cast<const float4*>(x + (size_t)row * D_MODEL);
    float4 v = xr[tid];

    const int lane = tid & 63, wave = tid >> 6;
    float s = v.x + v.y + v.z + v.w;
    #pragma unroll
    for (int off = 32; off > 0; off >>= 1) s += __shfl_down(s, off, 64);
    if (lane == 0) red[wave] = s;
    __syncthreads();
    float mu = (red[0] + red[1] + red[2] + red[3]) * (1.0f / D_MODEL);
    __syncthreads();

    float dx = v.x - mu, dy = v.y - mu, dz = v.z - mu, dw = v.w - mu;
    float ss = dx * dx + dy * dy + dz * dz + dw * dw;
    #pragma unroll
    for (int off = 32; off > 0; off >>= 1) ss += __shfl_down(ss, off, 64);
    if (lane == 0) red[wave] = ss;
    __syncthreads();
    float var = (red[0] + red[1] + red[2] + red[3]) * (1.0f / D_MODEL);
    float rs = rsqrtf(var + LN_EPS);

    const float4 gv = reinterpret_cast<const float4*>(gamma)[tid];
    const float4 bv = reinterpret_cast<const float4*>(beta)[tid];
    ushort4 o;
    o.x = f2bf(dx * rs * gv.x + bv.x);
    o.y = f2bf(dy * rs * gv.y + bv.y);
    o.z = f2bf(dz * rs * gv.z + bv.z);
    o.w = f2bf(dw * rs * gv.w + bv.w);
    reinterpret_cast<ushort4*>(xn + (size_t)row * D_MODEL)[tid] = o;
}

// ---------------------------------------------------------------------------
// 2a. 256x256 bf16 MFMA GEMM (TN), bf16 output. (GEMM1) — r12 known-good.
// ---------------------------------------------------------------------------
__global__ __launch_bounds__(512, 2) void gemm256_bf16(const short* __restrict__ A,
                                                       const short* __restrict__ B,
                                                       unsigned short* __restrict__ Cb,
                                                       int M, int N, int K) {
    __shared__ short lds[2 * 4 * 8192];   // 128 KiB

    const int tid = threadIdx.x;
    const int w = tid >> 6, l = tid & 63;

    const int id = blockIdx.y * gridDim.x + blockIdx.x;
    const int cpx = (gridDim.x * gridDim.y) >> 3;
    const int sid = (id & 7) * cpx + (id >> 3);
    const int row0 = (sid / gridDim.x) * 256;
    const int col0 = (sid % gridDim.x) * 256;

    const int wm = w >> 2;
    const int wn = w & 3;
    const int fr = l & 15;
    const int fc = (l >> 4) * 8;
    const int NT = K >> 6;

    const int qa = wm;
    const int qb = 2 + (wn >> 1);
    const int bb = (wn & 1) * 64;

    auto STAGE = [&](const short* __restrict__ G, int growbase, int k0,
                     int buf, int q) {
        #pragma unroll
        for (int j = 0; j < 2; ++j) {
            const int e = ((j * 8 + w) << 9) + l * 8;
            const int r = e >> 6;
            const int c = (e & 63) ^ ((r & 7) << 3);
            GLL16(G + (size_t)(growbase + r) * K + k0 + c,
                  &lds[buf * 32768 + q * 8192 + ((j * 8 + w) << 9)]);
        }
    };
    auto LDF = [&](int buf, int q, int r, int ks) -> bf16x8_t {
        const int c = (ks * 32 + fc) ^ ((r & 7) << 3);
        return *reinterpret_cast<const bf16x8_t*>(
            &lds[buf * 32768 + q * 8192 + r * 64 + c]);
    };

    f32x4_t acc[8][4] = {};
    bf16x8_t af[4][2], af2[4][2], bA[2][2], bB[2][2];

#define MFMA_Q(AF, mh, nh, BFR)                                                \
    do {                                                                       \
        _Pragma("unroll")                                                      \
        for (int mi = 0; mi < 4; ++mi)                                         \
            _Pragma("unroll")                                                  \
            for (int ni = 0; ni < 2; ++ni)                                     \
                _Pragma("unroll")                                              \
                for (int ks = 0; ks < 2; ++ks)                                 \
                    acc[(mh) * 4 + mi][(nh) * 2 + ni] =                        \
                        __builtin_amdgcn_mfma_f32_16x16x32_bf16(               \
                            AF[mi][ks], BFR[ni][ks],                           \
                            acc[(mh) * 4 + mi][(nh) * 2 + ni], 0, 0, 0);       \
    } while (0)

    STAGE(A, row0,       0, 0, 0);
    STAGE(A, row0 + 128, 0, 0, 1);
    STAGE(B, col0,       0, 0, 2);
    STAGE(B, col0 + 128, 0, 0, 3);
    if (NT > 1) {
        STAGE(B, col0,       64, 1, 2);
        STAGE(B, col0 + 128, 64, 1, 3);
        STAGE(A, row0,       64, 1, 0);
        asm volatile("s_waitcnt vmcnt(6)" ::: "memory");
    } else {
        asm volatile("s_waitcnt vmcnt(0)" ::: "memory");
    }
    BAR;

    for (int kt = 0; kt < NT; ++kt) {
        const int buf = kt & 1, nbuf = buf ^ 1;
        #pragma unroll
        for (int mi = 0; mi < 4; ++mi)
            #pragma unroll
            for (int ks = 0; ks < 2; ++ks)
                af[mi][ks] = LDF(buf, qa, mi * 16 + fr, ks);
        #pragma unroll
        for (int ni = 0; ni < 2; ++ni)
            #pragma unroll
            for (int ks = 0; ks < 2; ++ks)
                bA[ni][ks] = LDF(buf, qb, bb + ni * 16 + fr, ks);
        #pragma unroll
        for (int ni = 0; ni < 2; ++ni)
            #pragma unroll
            for (int ks = 0; ks < 2; ++ks)
                bB[ni][ks] = LDF(buf, qb, bb + 32 + ni * 16 + fr, ks);
        #pragma unroll
        for (int mi = 0; mi < 4; ++mi)
            #pragma unroll
            for (int ks = 0; ks < 2; ++ks)
                af2[mi][ks] = LDF(buf, qa, 64 + mi * 16 + fr, ks);
        if (kt + 1 < NT) STAGE(A, row0 + 128, (kt + 1) << 6, nbuf, 1);
        asm volatile("s_waitcnt lgkmcnt(0)" ::: "memory");
        BAR;
        if (kt + 2 < NT) {
            STAGE(B, col0,       (kt + 2) << 6, buf, 2);
            STAGE(B, col0 + 128, (kt + 2) << 6, buf, 3);
            STAGE(A, row0,       (kt + 2) << 6, buf, 0);
            asm volatile("s_waitcnt vmcnt(6)" ::: "memory");
        } else {
            asm volatile("s_waitcnt vmcnt(0)" ::: "memory");
        }
        BAR;
        __builtin_amdgcn_s_setprio(1);
        MFMA_Q(af,  0, 0, bA);
        MFMA_Q(af,  0, 1, bB);
        MFMA_Q(af2, 1, 1, bB);
        MFMA_Q(af2, 1, 0, bA);
        __builtin_amdgcn_s_setprio(0);
    }
#undef MFMA_Q

    const int cr = (l >> 4) * 4;
    const int cc = l & 15;
    #pragma unroll
    for (int m = 0; m < 8; ++m) {
        #pragma unroll
        for (int n = 0; n < 4; ++n) {
            size_t base = (size_t)(row0 + wm * 128 + m * 16 + cr) * N +
                          (col0 + wn * 64 + n * 16 + cc);
            #pragma unroll
            for (int j = 0; j < 4; ++j)
                Cb[base + (size_t)j * N] = f2bf(acc[m][n][j]);
        }
    }
}

// ---------------------------------------------------------------------------
// 2b. 256x128-tile bf16 MFMA GEMM (TN), f32 out + residual. (GEMM2)
//     3-buf 1-barrier + 4M×2N wave decomposition. — r14 known-good.
// ---------------------------------------------------------------------------
__global__ __launch_bounds__(512) void gemm_out(const short* __restrict__ A,
                                                const short* __restrict__ B,
                                                const float* __restrict__ add,
                                                float* __restrict__ C,
                                                int M, int N, int K) {
    __shared__ short lds[3 * 3 * 8192];   // 144 KiB

    const int tid = threadIdx.x;
    const int w = tid >> 6, l = tid & 63;

    const int id = blockIdx.y * gridDim.x + blockIdx.x;
    const int cpx = (gridDim.x * gridDim.y) >> 3;
    const int sid = (id & 7) * cpx + (id >> 3);
    const int row0 = (sid / gridDim.x) * 256;
    const int col0 = (sid % gridDim.x) * 128;

    const int wm = w >> 1;               // 0..3  (64-row strip)
    const int wn = w & 1;                // 0..1  (64-col strip)
    const int qa = wm >> 1;              // A quarter (0 or 1)
    const int lr0 = (wm & 1) * 64;       // local row base within quarter
    const int fr = l & 15;
    const int fc = (l >> 4) * 8;
    const int NT = K >> 6;

    auto STAGE = [&](const short* __restrict__ G, int growbase, int k0,
                     int buf, int q) {
        #pragma unroll
        for (int j = 0; j < 2; ++j) {
            const int e = ((j * 8 + w) << 9) + l * 8;
            const int r = e >> 6;
            const int c = (e & 63) ^ ((r & 7) << 3);
            GLL16(G + (size_t)(growbase + r) * K + k0 + c,
                  &lds[buf * 24576 + q * 8192 + ((j * 8 + w) << 9)]);
        }
    };
    auto LDF = [&](int buf, int q, int r, int ks) -> bf16x8_t {
        const int c = (ks * 32 + fc) ^ ((r & 7) << 3);
        return *reinterpret_cast<const bf16x8_t*>(
            &lds[buf * 24576 + q * 8192 + r * 64 + c]);
    };

    f32x4_t acc[4][4] = {};
    bf16x8_t af[4][2], bf[4][2];

    STAGE(A, row0,       0, 0, 0);
    STAGE(A, row0 + 128, 0, 0, 1);
    STAGE(B, col0,       0, 0, 2);
    if (NT > 1) {
        STAGE(A, row0,       64, 1, 0);
        STAGE(A, row0 + 128, 64, 1, 1);
        STAGE(B, col0,       64, 1, 2);
        asm volatile("s_waitcnt vmcnt(6)" ::: "memory");
    } else {
        asm volatile("s_waitcnt vmcnt(0)" ::: "memory");
    }

    int buf = 0;
    for (int kt = 0; kt < NT; ++kt) {
        BAR;
        #pragma unroll
        for (int mi = 0; mi < 4; ++mi)
            #pragma unroll
            for (int ks = 0; ks < 2; ++ks)
                af[mi][ks] = LDF(buf, qa, lr0 + mi * 16 + fr, ks);
        #pragma unroll
        for (int ni = 0; ni < 4; ++ni)
            #pragma unroll
            for (int ks = 0; ks < 2; ++ks)
                bf[ni][ks] = LDF(buf, 2, wn * 64 + ni * 16 + fr, ks);
        __builtin_amdgcn_s_setprio(1);
        #pragma unroll
        for (int mi = 0; mi < 4; ++mi)
            #pragma unroll
            for (int ni = 0; ni < 4; ++ni)
                #pragma unroll
                for (int ks = 0; ks < 2; ++ks)
                    acc[mi][ni] = __builtin_amdgcn_mfma_f32_16x16x32_bf16(
                        af[mi][ks], bf[ni][ks], acc[mi][ni], 0, 0, 0);
        __builtin_amdgcn_s_setprio(0);
        if (kt + 2 < NT) {
            const int sb = (buf + 2) % 3;
            STAGE(A, row0,       (kt + 2) << 6, sb, 0);
            STAGE(A, row0 + 128, (kt + 2) << 6, sb, 1);
            STAGE(B, col0,       (kt + 2) << 6, sb, 2);
            asm volatile("s_waitcnt vmcnt(6)" ::: "memory");
        } else {
            asm volatile("s_waitcnt vmcnt(0)" ::: "memory");
        }
        buf = (buf + 1) % 3;
    }

    const int cr = (l >> 4) * 4;
    const int cc = l & 15;
    #pragma unroll
    for (int mi = 0; mi < 4; ++mi) {
        #pragma unroll
        for (int ni = 0; ni < 4; ++ni) {
            size_t base = (size_t)(row0 + wm * 64 + mi * 16 + cr) * N +
                          (col0 + wn * 64 + ni * 16 + cc);
            #pragma unroll
            for (int j = 0; j < 4; ++j)
                C[base + (size_t)j * N] = acc[mi][ni][j] + add[base + (size_t)j * N];
        }
    }
}

// ---------------------------------------------------------------------------
// 3. V = x_part @ Bm^T via MFMA (K=2048). 2 waves/block split-K.
// ---------------------------------------------------------------------------
__global__ __launch_bounds__(128) void v_mfma(const unsigned short* __restrict__ xz,
                                              const unsigned short* __restrict__ Bmb,
                                              float* __restrict__ V) {
    __shared__ float part[2][16][16];
    const int tid = threadIdx.x;
    const int wv = tid >> 6;             // 0..1 : K half
    const int l = tid & 63;
    const int r0 = blockIdx.x * 16;
    const int fr = l & 15;
    const int fk = (l >> 4) * 8;
    const int kbase = wv * (D_INNER / 2);

    const unsigned short* aP = xz + (size_t)(r0 + fr) * (2 * D_INNER) + kbase + fk;
    const unsigned short* bP = Bmb + fr * D_INNER + kbase + fk;

    f32x4_t a0 = {}, a1 = {}, a2 = {}, a3 = {};
    #pragma unroll 2
    for (int k0 = 0; k0 < D_INNER / 2; k0 += 128) {
        a0 = __builtin_amdgcn_mfma_f32_16x16x32_bf16(
            *reinterpret_cast<const bf16x8_t*>(aP + k0),
            *reinterpret_cast<const bf16x8_t*>(bP + k0), a0, 0, 0, 0);
        a1 = __builtin_amdgcn_mfma_f32_16x16x32_bf16(
            *reinterpret_cast<const bf16x8_t*>(aP + k0 + 32),
            *reinterpret_cast<const bf16x8_t*>(bP + k0 + 32), a1, 0, 0, 0);
        a2 = __builtin_amdgcn_mfma_f32_16x16x32_bf16(
            *reinterpret_cast<const bf16x8_t*>(aP + k0 + 64),
            *reinterpret_cast<const bf16x8_t*>(bP + k0 + 64), a2, 0, 0, 0);
        a3 = __builtin_amdgcn_mfma_f32_16x16x32_bf16(
            *reinterpret_cast<const bf16x8_t*>(aP + k0 + 96),
            *reinterpret_cast<const bf16x8_t*>(bP + k0 + 96), a3, 0, 0, 0);
    }

    const int cr = (l >> 4) * 4;
    const int cc = l & 15;
    #pragma unroll
    for (int j = 0; j < 4; ++j)
        part[wv][cr + j][cc] = a0[j] + a1[j] + a2[j] + a3[j];
    __syncthreads();
    if (tid < 64) {
        #pragma unroll
        for (int j = 0; j < 4; ++j)
            V[(size_t)(r0 + cr + j) * D_STATE + cc] =
                part[0][cr + j][cc] + part[1][cr + j][cc];
    }
}

// ---------------------------------------------------------------------------
// 4. Fused scan: blocks 0..31 = parallel cumsum (A == I); block 32 =
//    sequential general-A fallback. Both self-check A; exactly one side runs.
// ---------------------------------------------------------------------------
#define SCAN_CHUNK 256
__global__ __launch_bounds__(256) void scan_fused(const float* __restrict__ V,
                                                  const float* __restrict__ A,
                                                  float* __restrict__ S) {
    const int tid = threadIdx.x;
    __shared__ int nid;
    if (blockIdx.x < 32) {
        if (tid == 0) nid = 0;
        __syncthreads();
        {
            const float ex = ((tid >> 4) == (tid & 15)) ? 1.0f : 0.0f;
            if (A[tid] != ex) atomicOr(&nid, 1);
        }
        __syncthreads();
        if (nid) return;

        const int p = blockIdx.x;
        const int b = p >> 4, s = p & 15;
        const float* vb = V + (size_t)b * SEQ * D_STATE + s;
        float* sb = S + (size_t)b * SEQ * D_STATE + s;

        const int t0 = tid * 16;
        float v[16];
        float run = 0.0f;
        #pragma unroll
        for (int j = 0; j < 16; ++j) {
            run += vb[(size_t)(t0 + j) * D_STATE];
            v[j] = run;
        }

        const float tot = run;
        float sc = tot;
        #pragma unroll
        for (int off = 1; off < 64; off <<= 1) {
            float n = __shfl_up(sc, off, 64);
            if ((tid & 63) >= off) sc += n;
        }
        __shared__ float wtot[4];
        if ((tid & 63) == 63) wtot[tid >> 6] = sc;
        __syncthreads();
        float woff = 0.0f;
        #pragma unroll
        for (int w2 = 0; w2 < 4; ++w2)
            if (w2 < (tid >> 6)) woff += wtot[w2];
        const float excl = sc - tot + woff;

        #pragma unroll
        for (int j = 0; j < 16; ++j)
            sb[(size_t)(t0 + j) * D_STATE] = v[j] + excl;
        return;
    }

    // ---- sequential general-A path (block 32)
    if (tid == 0) nid = 0;
    __syncthreads();
    {
        const float ex = ((tid >> 4) == (tid & 15)) ? 1.0f : 0.0f;
        if (A[tid] != ex) atomicOr(&nid, 1);
    }
    __syncthreads();
    if (nid == 0) return;   // identity -> parallel blocks handled it

    __shared__ float Al[D_STATE * D_STATE];
    __shared__ float Vl[2 * SCAN_CHUNK * D_STATE];
    __shared__ float Sl[2 * SCAN_CHUNK * D_STATE];

    Al[tid] = A[tid];
    __syncthreads();

    float st = 0.0f;
    const int bb = (tid >> 4) & 1;
    const int ss = tid & 15;

    for (int t0 = 0; t0 < SEQ; t0 += SCAN_CHUNK) {
        for (int idx = tid; idx < 2 * SCAN_CHUNK * D_STATE; idx += 256) {
            int b = idx >> 12;
            int rem = idx & 4095;
            Vl[idx] = V[((size_t)(b * SEQ + t0) * D_STATE) + rem];
        }
        __syncthreads();

        if (tid < 32) {
            float* vb = Vl + bb * SCAN_CHUNK * D_STATE + ss;
            float* sb = Sl + bb * SCAN_CHUNK * D_STATE + ss;
            for (int t = 0; t < SCAN_CHUNK; ++t) {
                float ns = vb[t * D_STATE];
                #pragma unroll
                for (int s2 = 0; s2 < D_STATE; ++s2) {
                    float other = __shfl(st, (tid & 16) | s2, 64);
                    ns = fmaf(Al[ss * D_STATE + s2], other, ns);
                }
                st = ns;
                sb[t * D_STATE] = st;
            }
        }
        __syncthreads();

        for (int idx = tid; idx < 2 * SCAN_CHUNK * D_STATE; idx += 256) {
            int b = idx >> 12;
            int rem = idx & 4095;
            S[((size_t)(b * SEQ + t0) * D_STATE) + rem] = Sl[idx];
        }
        __syncthreads();
    }
}

// ---------------------------------------------------------------------------
// 5. y = (silu(conv(x_part)) + S @ Cm) * sigmoid(z)  -> bf16 output.
//    r14 known-good 2-cols/thread form (r15's 4-col variant spilled cm[] to
//    scratch: VGPR 68 < 90 needed -> 77 us. REVERTED).
// ---------------------------------------------------------------------------
__global__ __launch_bounds__(256) void y_kernel(const unsigned short* __restrict__ xz,
                                                const float* __restrict__ S,
                                                const float* __restrict__ Cm,
                                                const float* __restrict__ convw,
                                                const float* __restrict__ convb,
                                                unsigned short* __restrict__ y) {
    const int tid = threadIdx.x;
    const int i0 = blockIdx.x * 512 + tid * 2;
    const int r0 = blockIdx.y * 64;
    const int tb0 = r0 & (SEQ - 1);

    const float4 w0 = *reinterpret_cast<const float4*>(&convw[i0 * D_CONV]);
    const float4 w1 = *reinterpret_cast<const float4*>(&convw[(i0 + 1) * D_CONV]);
    const float cb0 = convb[i0], cb1 = convb[i0 + 1];
    float cm0[D_STATE], cm1[D_STATE];
    #pragma unroll
    for (int s = 0; s < D_STATE; ++s) {
        float2 c = *reinterpret_cast<const float2*>(&Cm[s * D_INNER + i0]);
        cm0[s] = c.x; cm1[s] = c.y;
    }

    float2 xm1 = make_float2(0.f, 0.f), xm2 = xm1, xm3 = xm1;
    if (tb0 >= 1) { ushort2 u = *reinterpret_cast<const ushort2*>(&xz[(size_t)(r0 - 1) * (2 * D_INNER) + i0]); xm1 = make_float2(bf2f(u.x), bf2f(u.y)); }
    if (tb0 >= 2) { ushort2 u = *reinterpret_cast<const ushort2*>(&xz[(size_t)(r0 - 2) * (2 * D_INNER) + i0]); xm2 = make_float2(bf2f(u.x), bf2f(u.y)); }
    if (tb0 >= 3) { ushort2 u = *reinterpret_cast<const ushort2*>(&xz[(size_t)(r0 - 3) * (2 * D_INNER) + i0]); xm3 = make_float2(bf2f(u.x), bf2f(u.y)); }

    for (int r = r0; r < r0 + 64; ++r) {
        const ushort2 xu = *reinterpret_cast<const ushort2*>(&xz[(size_t)r * (2 * D_INNER) + i0]);
        const ushort2 zu = *reinterpret_cast<const ushort2*>(&xz[(size_t)r * (2 * D_INNER) + D_INNER + i0]);
        const float2 x0 = make_float2(bf2f(xu.x), bf2f(xu.y));

        float a0 = cb0;
        a0 = fmaf(w0.x, xm3.x, a0); a0 = fmaf(w0.y, xm2.x, a0);
        a0 = fmaf(w0.z, xm1.x, a0); a0 = fmaf(w0.w, x0.x, a0);
        float a1 = cb1;
        a1 = fmaf(w1.x, xm3.y, a1); a1 = fmaf(w1.y, xm2.y, a1);
        a1 = fmaf(w1.z, xm1.y, a1); a1 = fmaf(w1.w, x0.y, a1);

        const float xc0 = a0 / (1.0f + expf(-a0));
        const float xc1 = a1 / (1.0f + expf(-a1));

        const float4* Sp = reinterpret_cast<const float4*>(S + (size_t)r * D_STATE);
        const float4 s0 = Sp[0], s1 = Sp[1], s2 = Sp[2], s3 = Sp[3];
        const float sv[D_STATE] = {s0.x, s0.y, s0.z, s0.w, s1.x, s1.y, s1.z, s1.w,
                                   s2.x, s2.y, s2.z, s2.w, s3.x, s3.y, s3.z, s3.w};
        float sc0 = 0.f, sc1 = 0.f;
        #pragma unroll
        for (int s = 0; s < D_STATE; ++s) {
            sc0 = fmaf(sv[s], cm0[s], sc0);
            sc1 = fmaf(sv[s], cm1[s], sc1);
        }

        const float z0 = bf2f(zu.x), z1 = bf2f(zu.y);
        const float g0 = 1.0f / (1.0f + expf(-z0));
        const float g1 = 1.0f / (1.0f + expf(-z1));

        ushort2 o;
        o.x = f2bf((xc0 + sc0) * g0);
        o.y = f2bf((xc1 + sc1) * g1);
        *reinterpret_cast<ushort2*>(&y[(size_t)r * D_INNER + i0]) = o;

        xm3 = xm2; xm2 = xm1; xm1 = x0;
    }
}

// ---------------------------------------------------------------------------
// launch
// ---------------------------------------------------------------------------
extern "C" void kernel_launch(void* const* d_in, const int* in_sizes, int n_in,
                              void* d_out, int out_size, void* d_ws, size_t ws_size,
                              hipStream_t stream) {
    const float* x      = (const float*)d_in[0];
    const float* ln_g   = (const float*)d_in[1];
    const float* ln_b   = (const float*)d_in[2];
    const float* W_in   = (const float*)d_in[3];
    const float* conv_w = (const float*)d_in[4];
    const float* conv_b = (const float*)d_in[5];
    const float* W_out  = (const float*)d_in[6];
    const float* A      = (const float*)d_in[7];
    const float* Bm     = (const float*)d_in[8];
    const float* Cm     = (const float*)d_in[9];
    float* out = (float*)d_out;

    // workspace layout
    float* ws = (float*)d_ws;
    float* V  = ws;                                        // 8192*16 f32
    float* S  = V + (size_t)NROW * D_STATE;                // 8192*16 f32
    unsigned short* xz_bf  = (unsigned short*)(S + (size_t)NROW * D_STATE);
    unsigned short* xn_bf  = xz_bf  + (size_t)NROW * 2 * D_INNER;
    unsigned short* Win_bf = xn_bf  + (size_t)NROW * D_MODEL;
    unsigned short* Wout_bf= Win_bf + (size_t)(2 * D_INNER) * D_MODEL;
    unsigned short* Bm_bf  = Wout_bf + (size_t)D_MODEL * D_INNER;
    unsigned short* y_bf   = Bm_bf  + (size_t)D_STATE * D_INNER;

    // 0+1. weight conversion + LayerNorm (fused launch, block-per-row LN)
    pre_kernel<<<CVT_BLOCKS + NROW, 256, 0, stream>>>(
        x, ln_g, ln_b, W_in, W_out, Bm, xn_bf, Win_bf, Wout_bf, Bm_bf);

    // 2. xz = xn @ W_in^T -> bf16   (M=8192, N=4096, K=1024), 2-barrier/kt
    gemm256_bf16<<<dim3((2 * D_INNER) / 256, NROW / 256), 512, 0, stream>>>(
        (const short*)xn_bf, (const short*)Win_bf, xz_bf,
        NROW, 2 * D_INNER, D_MODEL);

    // 3. V = x_part @ Bm^T  (MFMA, split-K x2, 4 ILP chains per wave)
    v_mfma<<<NROW / 16, 128, 0, stream>>>(xz_bf, Bm_bf, V);

    // 4. fused scan (blocks 0-31 parallel, block 32 sequential fallback)
    scan_fused<<<33, 256, 0, stream>>>(V, A, S);

    // 5. y = (silu(conv(x_part)) + S@Cm) * sigmoid(z) -> bf16 (2 cols/thr)
    y_kernel<<<dim3(D_INNER / 512, NROW / 64), 256, 0, stream>>>(
        xz_bf, S, Cm, conv_w, conv_b, y_bf);

    // 6. out = x + y @ W_out^T  (M=8192, N=1024, K=2048), 3-buf 1-bar, 4Mx2N
    gemm_out<<<dim3(D_MODEL / 128, NROW / 256), 512, 0, stream>>>(
        (const short*)y_bf, (const short*)Wout_bf, x, out,
        NROW, D_MODEL, D_INNER);
}